// Round 2
// baseline (174.280 us; speedup 1.0000x reference)
//
#include <hip/hip_runtime.h>

#define BATCH   16384
#define NUM_NUM 32
#define NUM_CAT 32
#define CARD    128
#define OUT_F   32
#define XSTRIDE (NUM_NUM + NUM_CAT * CARD)   // 4128
#define OSTRIDE (NUM_NUM + NUM_CAT * OUT_F)  // 1056

#define TRB   512          // rows per block
#define CK    16           // K chunk staged in LDS
#define XPAD  20           // x_s row stride (floats): 16 + 4 pad -> 16-row b128 pattern is 2-way only
#define NCHUNK (CARD / CK) // 8

// One block = one feature f x 512 batch rows. 256 threads.
// Thread tile 8 rows x 8 cols; c-step 4 -> per step 16x ds_read_b128 vs 512 FMA-cycles.
// LDS: W[f] 16KB + x_s 512x20 f32 = 40KB -> 56KB -> 2 blocks/CU (8 waves).
__global__ __launch_bounds__(256, 2) void emb_gemm(const float* __restrict__ x,
                                                   const float* __restrict__ W,
                                                   const float* __restrict__ bias,
                                                   float* __restrict__ out) {
    __shared__ float w_s[CARD][OUT_F];  // [c][o], stride 32 -> W b128 reads conflict-free (4 og quads)
    __shared__ float x_s[TRB][XPAD];

    const int f    = blockIdx.y;
    const int row0 = blockIdx.x * TRB;
    const int tid  = threadIdx.x;

    const int og = tid & 3;   // 4 col-groups of 8 outputs
    const int rg = tid >> 2;  // 64 row-groups of 8 rows

    // Stage W[f]: 1024 float4, 4 per thread.
    {
        const float4* wg  = (const float4*)(W + (size_t)f * CARD * OUT_F);
        float4*       ws4 = (float4*)&w_s[0][0];
#pragma unroll
        for (int i = 0; i < 4; ++i) ws4[i * 256 + tid] = wg[i * 256 + tid];
    }

    const float* xg_base = x + (size_t)row0 * XSTRIDE + NUM_NUM + f * CARD;

    float4 st[8];
    // Prologue: load + write chunk 0 (512 rows x 16 c = 2048 float4, 8/thread).
#pragma unroll
    for (int it = 0; it < 8; ++it) {
        int idx = it * 256 + tid;
        int r   = idx >> 2;
        int c4  = (idx & 3) << 2;
        st[it]  = *(const float4*)(xg_base + (size_t)r * XSTRIDE + c4);
    }
#pragma unroll
    for (int it = 0; it < 8; ++it) {
        int idx = it * 256 + tid;
        *(float4*)&x_s[idx >> 2][(idx & 3) << 2] = st[it];
    }
    __syncthreads();

    float acc[8][8];
#pragma unroll
    for (int j = 0; j < 8; ++j)
#pragma unroll
        for (int k = 0; k < 8; ++k) acc[j][k] = 0.0f;

    for (int ck = 0; ck < NCHUNK; ++ck) {
        // T14: issue next chunk's global loads before compute; write after barrier.
        if (ck < NCHUNK - 1) {
            const float* xg = xg_base + (ck + 1) * CK;
#pragma unroll
            for (int it = 0; it < 8; ++it) {
                int idx = it * 256 + tid;
                int r   = idx >> 2;
                int c4  = (idx & 3) << 2;
                st[it]  = *(const float4*)(xg + (size_t)r * XSTRIDE + c4);
            }
        }

#pragma unroll 2
        for (int cs = 0; cs < CK; cs += 4) {
            float4 xv[8];
#pragma unroll
            for (int j = 0; j < 8; ++j) xv[j] = *(const float4*)&x_s[rg * 8 + j][cs];
#pragma unroll
            for (int cc = 0; cc < 4; ++cc) {
                const int c  = ck * CK + cs + cc;
                float4 w0 = *(const float4*)&w_s[c][og * 8];
                float4 w1 = *(const float4*)&w_s[c][og * 8 + 4];
#pragma unroll
                for (int j = 0; j < 8; ++j) {
                    float xf = ((const float*)&xv[j])[cc];
                    acc[j][0] += xf * w0.x;
                    acc[j][1] += xf * w0.y;
                    acc[j][2] += xf * w0.z;
                    acc[j][3] += xf * w0.w;
                    acc[j][4] += xf * w1.x;
                    acc[j][5] += xf * w1.y;
                    acc[j][6] += xf * w1.z;
                    acc[j][7] += xf * w1.w;
                }
            }
        }

        __syncthreads();  // all reads of x_s done
        if (ck < NCHUNK - 1) {
#pragma unroll
            for (int it = 0; it < 8; ++it) {
                int idx = it * 256 + tid;
                *(float4*)&x_s[idx >> 2][(idx & 3) << 2] = st[it];
            }
            __syncthreads();
        }
    }

    // Epilogue: bias + store 8 rows x 2 float4.
    float4 b0 = *(const float4*)(bias + f * OUT_F + og * 8);
    float4 b1 = *(const float4*)(bias + f * OUT_F + og * 8 + 4);
#pragma unroll
    for (int j = 0; j < 8; ++j) {
        size_t obase = (size_t)(row0 + rg * 8 + j) * OSTRIDE + NUM_NUM + f * OUT_F + og * 8;
        float4 o0, o1;
        o0.x = acc[j][0] + b0.x; o0.y = acc[j][1] + b0.y;
        o0.z = acc[j][2] + b0.z; o0.w = acc[j][3] + b0.w;
        o1.x = acc[j][4] + b1.x; o1.y = acc[j][5] + b1.y;
        o1.z = acc[j][6] + b1.z; o1.w = acc[j][7] + b1.w;
        *(float4*)(out + obase)     = o0;
        *(float4*)(out + obase + 4) = o1;
    }

    // Fold the numeric-column passthrough into the f==0 blocks: 512 rows x 8 float4.
    if (f == 0) {
#pragma unroll
        for (int it = 0; it < 16; ++it) {
            int idx = it * 256 + tid;  // 4096 float4
            int r   = idx >> 3;
            int c4  = (idx & 7) << 2;
            *(float4*)(out + (size_t)(row0 + r) * OSTRIDE + c4) =
                *(const float4*)(x + (size_t)(row0 + r) * XSTRIDE + c4);
        }
    }
}

extern "C" void kernel_launch(void* const* d_in, const int* in_sizes, int n_in,
                              void* d_out, int out_size, void* d_ws, size_t ws_size,
                              hipStream_t stream) {
    const float* x    = (const float*)d_in[0];
    const float* W    = (const float*)d_in[1];
    const float* bias = (const float*)d_in[2];
    float*       out  = (float*)d_out;

    dim3 grid(BATCH / TRB, NUM_CAT);
    emb_gemm<<<grid, 256, 0, stream>>>(x, W, bias, out);
}

// Round 3
// 163.196 us; speedup vs baseline: 1.0679x; 1.0679x over previous
//
#include <hip/hip_runtime.h>
#include <stdint.h>

#define BATCH   16384
#define NUM_NUM 32
#define NUM_CAT 32
#define CARD    128
#define OUT_F   32
#define XSTRIDE 4128   // NUM_NUM + NUM_CAT*CARD
#define OSTRIDE 1056   // NUM_NUM + NUM_CAT*OUT_F

#define TRB    256          // rows per block
#define CK     8            // K cols per chunk
#define NCHUNK (CARD / CK)  // 16
#define QPB    (TRB * CK / 4)  // 512 float4 slots per x buffer

typedef const __attribute__((address_space(1))) void* as1_cvp;
typedef __attribute__((address_space(3))) void*       as3_vp;

// 128 threads = 2 waves. Thread tile: 8 rows x 8 outputs (og=tid&3, rg=tid>>2 in 0..31).
// x_s layout: swizzled float4 quads, phys P = logical Q ^ ((Q>>4)&7) (involution; bits 4..6
// are the rg bits of the row, bits 0..2 get XORed). Read set per wave instr: 16 distinct
// addresses covering all 8 bank-quads exactly 2x -> conflict-free.
// Staging: global_load_lds width 16, linear LDS dest, inverse-swizzled global source
// (rule 21: same involution on source permutes lanes within identical 64B/32B segments).
// LDS: w_s 16KB + x_s 2x8KB = 32KB -> 5 blocks/CU = 10 waves/CU.
__global__ __launch_bounds__(128, 3) void emb_gemm(const float* __restrict__ x,
                                                   const float* __restrict__ Wm,
                                                   const float* __restrict__ bias,
                                                   float* __restrict__ out) {
    __shared__ float  w_s[CARD][OUT_F];  // [c][o], 16 KB
    __shared__ float4 x_s[2][QPB];       // 2 x 8 KB, swizzled quads

    const int f    = blockIdx.y;
    const int row0 = blockIdx.x * TRB;
    const int tid  = threadIdx.x;
    const int lane = tid & 63;
    const int wv   = tid >> 6;   // 0..1
    const int og   = tid & 3;    // 4 output groups of 8
    const int rg   = tid >> 2;   // 32 row groups of 8

    // ---- stage W[f] once: 1024 float4, 8 per thread ----
    {
        const float4* wg  = (const float4*)(Wm + (size_t)f * (CARD * OUT_F));
        float4*       ws4 = (float4*)&w_s[0][0];
#pragma unroll
        for (int i = 0; i < 8; ++i) ws4[i * 128 + tid] = wg[i * 128 + tid];
    }

    const float* xg = x + (size_t)row0 * XSTRIDE + NUM_NUM + f * CARD;

    // Per-lane staging source offsets (chunk-independent). Instr i = wv*4+s writes
    // phys quads [i*64, i*64+64); this lane supplies phys quad P = i*64+lane, whose
    // logical quad is Q = P ^ ((P>>4)&7) -> row r = Q>>1, col-quad q = Q&1.
    int soff[4];
#pragma unroll
    for (int s = 0; s < 4; ++s) {
        int P   = (wv * 4 + s) * 64 + lane;
        int Q   = P ^ ((P >> 4) & 7);
        soff[s] = (Q >> 1) * XSTRIDE + (Q & 1) * 4;
    }

    // prologue: stage chunk 0 -> buf 0
#pragma unroll
    for (int s = 0; s < 4; ++s)
        __builtin_amdgcn_global_load_lds((as1_cvp)(xg + soff[s]),
                                         (as3_vp)&x_s[0][(wv * 4 + s) * 64], 16, 0, 0);
    __syncthreads();  // drains vmcnt + w_s writes

    float acc[8][8];
#pragma unroll
    for (int j = 0; j < 8; ++j)
#pragma unroll
        for (int k = 0; k < 8; ++k) acc[j][k] = 0.0f;

    for (int ck = 0; ck < NCHUNK; ++ck) {
        const int cur = ck & 1;
        // async-stage next chunk into the other buffer (no barrier until loop end)
        if (ck + 1 < NCHUNK) {
            const float* xs = xg + (ck + 1) * CK;
#pragma unroll
            for (int s = 0; s < 4; ++s)
                __builtin_amdgcn_global_load_lds((as1_cvp)(xs + soff[s]),
                                                 (as3_vp)&x_s[cur ^ 1][(wv * 4 + s) * 64], 16, 0, 0);
        }

        const float4* xb = x_s[cur];
#pragma unroll
        for (int sq = 0; sq < 2; ++sq) {   // two 4-col steps
            float4 xv[8];
#pragma unroll
            for (int j = 0; j < 8; ++j) {
                int Q = (rg * 8 + j) * 2 + sq;   // logical quad; Q>>4 == rg
                xv[j] = xb[Q ^ (rg & 7)];
            }
#pragma unroll
            for (int cc = 0; cc < 4; ++cc) {
                const int    c  = ck * CK + sq * 4 + cc;
                const float4 w0 = *(const float4*)&w_s[c][og * 8];
                const float4 w1 = *(const float4*)&w_s[c][og * 8 + 4];
#pragma unroll
                for (int j = 0; j < 8; ++j) {
                    const float xf = (&xv[j].x)[cc];
                    acc[j][0] += xf * w0.x;  acc[j][1] += xf * w0.y;
                    acc[j][2] += xf * w0.z;  acc[j][3] += xf * w0.w;
                    acc[j][4] += xf * w1.x;  acc[j][5] += xf * w1.y;
                    acc[j][6] += xf * w1.z;  acc[j][7] += xf * w1.w;
                }
            }
        }
        __syncthreads();  // staged data visible; current buffer free for reuse
    }

    // ---- epilogue: bias + 8 rows x 2 float4 stores ----
    const float4 b0 = *(const float4*)(bias + f * OUT_F + og * 8);
    const float4 b1 = *(const float4*)(bias + f * OUT_F + og * 8 + 4);
#pragma unroll
    for (int j = 0; j < 8; ++j) {
        size_t ob = (size_t)(row0 + rg * 8 + j) * OSTRIDE + NUM_NUM + f * OUT_F + og * 8;
        float4 o0, o1;
        o0.x = acc[j][0] + b0.x; o0.y = acc[j][1] + b0.y;
        o0.z = acc[j][2] + b0.z; o0.w = acc[j][3] + b0.w;
        o1.x = acc[j][4] + b1.x; o1.y = acc[j][5] + b1.y;
        o1.z = acc[j][6] + b1.z; o1.w = acc[j][7] + b1.w;
        *(float4*)(out + ob)     = o0;
        *(float4*)(out + ob + 4) = o1;
    }

    // ---- numeric passthrough folded into f==0 blocks: 256 rows x 8 float4 ----
    if (f == 0) {
#pragma unroll
        for (int it = 0; it < 16; ++it) {
            int idx = it * 128 + tid;   // 2048 float4
            int r   = idx >> 3;
            int c4  = (idx & 7) << 2;
            *(float4*)(out + (size_t)(row0 + r) * OSTRIDE + c4) =
                *(const float4*)(x + (size_t)(row0 + r) * XSTRIDE + c4);
        }
    }
}

extern "C" void kernel_launch(void* const* d_in, const int* in_sizes, int n_in,
                              void* d_out, int out_size, void* d_ws, size_t ws_size,
                              hipStream_t stream) {
    const float* x    = (const float*)d_in[0];
    const float* W    = (const float*)d_in[1];
    const float* bias = (const float*)d_in[2];
    float*       out  = (float*)d_out;

    dim3 grid(BATCH / TRB, NUM_CAT);
    emb_gemm<<<grid, 128, 0, stream>>>(x, W, bias, out);
}